// Round 1
// 1687.763 us; speedup vs baseline: 1.0491x; 1.0491x over previous
//
#include <hip/hip_runtime.h>

// HiPPO-LegT forward scan, fp32.
//   c_t = c_{t-1} @ A^T + f_t * B    (512 sequences, N=256, L=1024)
//
// R1 polish. Evidence from baseline counters: VGPR_Count=48 although the kernel
// holds a 64-float A fragment => A was demoted out of arch VGPRs (AGPR/remat
// round-trips every step), inflating VALU issue (VALUBusy=70% vs ~31% pure-FMA
// floor). Fixes this round, mapping unchanged (row, cb in 0..3; CPAD=68 LDS
// double buffer; 1 WG/CU):
//   1. in-loop empty-asm "+v" pins force the A fragment to stay in arch VGPRs
//   2. v_pk_fma_f32 via float2 ext-vectors: 128 -> 64 FMA instr per thread/step
//   3. quad reduce via DPP quad_perm adds (VALU pipe) instead of ds_swizzle
// Prediction: dur ~1570us -> ~600-750us, VGPR_Count -> ~110-128, VALUBusy down
// toward 45-55%. Falsifier: unchanged dur + VALUBusy ~30% => LDS-return-BW
// bound => next round 4x16 thread tiles (8 ds_read_b128/step).

#define LSTEPS 1024
#define CPAD 68

typedef float v2f __attribute__((ext_vector_type(2)));

__device__ __forceinline__ float quad_reduce(float v) {
    // sum over the 4 lanes of each quad; same association as shfl_xor(1) then
    // shfl_xor(2), but on the VALU pipe (v_mov_dpp/v_add_f32_dpp), no LDS.
    v += __int_as_float(__builtin_amdgcn_update_dpp(
            0, __float_as_int(v), 0xB1, 0xF, 0xF, false));  // quad_perm [1,0,3,2]
    v += __int_as_float(__builtin_amdgcn_update_dpp(
            0, __float_as_int(v), 0x4E, 0xF, 0xF, false));  // quad_perm [2,3,0,1]
    return v;
}

__global__ __launch_bounds__(1024, 4) void hippo_legt_kernel(
    const float* __restrict__ inp,   // (512, 1024) = (B*M, L), contiguous in t
    const float* __restrict__ A,     // (256, 256) row-major (discrete Ad)
    const float* __restrict__ Bvec,  // (256)      (discrete Bd)
    float* __restrict__ out)         // (1024, 512, 256)
{
    __shared__ __attribute__((aligned(16))) float cbuf[2][2][4][CPAD]; // [buf][seq][blk][pad]
    __shared__ __attribute__((aligned(16))) float fbuf[2][LSTEPS];

    const int tid  = threadIdx.x;
    const int row  = tid >> 2;   // 0..255
    const int cb   = tid & 3;    // col-block 0..3
    const int seq0 = blockIdx.x * 2;

    // A fragment: A[row][cb*64 + k], k = 0..63, held as 32 float2 (64 VGPRs).
    v2f a2[32];
    {
        const float4* Ar = reinterpret_cast<const float4*>(A + row * 256 + cb * 64);
        #pragma unroll
        for (int q = 0; q < 16; ++q) {
            const float4 t = Ar[q];
            v2f lo = {t.x, t.y};
            v2f hi = {t.z, t.w};
            a2[2 * q]     = lo;
            a2[2 * q + 1] = hi;
        }
    }
    float bd = Bvec[row];

    // Preload f for both sequences: 2048 floats = 512 float4, coalesced.
    if (tid < 512) {
        reinterpret_cast<float4*>(&fbuf[0][0])[tid] =
            reinterpret_cast<const float4*>(inp + (size_t)seq0 * LSTEPS)[tid];
    }
    // Zero initial state buffer (buf 0).
    if (tid < 2 * 4 * CPAD) {
        (&cbuf[0][0][0][0])[tid] = 0.0f;
    }
    __syncthreads();

    float* outp = out + (size_t)seq0 * 256 + row;

    auto step = [&](int cur, int nxt, int t) {
        // Pin the A fragment (and bd) into arch VGPRs for this iteration: the
        // "+v" outputs make the values opaque, so the allocator can neither
        // rematerialize them from memory nor park them in AGPRs between uses.
        asm volatile("" : "+v"(a2[0]), "+v"(a2[1]), "+v"(a2[2]), "+v"(a2[3]),
                          "+v"(a2[4]), "+v"(a2[5]), "+v"(a2[6]), "+v"(a2[7]));
        asm volatile("" : "+v"(a2[8]),  "+v"(a2[9]),  "+v"(a2[10]), "+v"(a2[11]),
                          "+v"(a2[12]), "+v"(a2[13]), "+v"(a2[14]), "+v"(a2[15]));
        asm volatile("" : "+v"(a2[16]), "+v"(a2[17]), "+v"(a2[18]), "+v"(a2[19]),
                          "+v"(a2[20]), "+v"(a2[21]), "+v"(a2[22]), "+v"(a2[23]));
        asm volatile("" : "+v"(a2[24]), "+v"(a2[25]), "+v"(a2[26]), "+v"(a2[27]),
                          "+v"(a2[28]), "+v"(a2[29]), "+v"(a2[30]), "+v"(a2[31]),
                          "+v"(bd));

        const float f0 = fbuf[0][t];               // wave-uniform LDS broadcast
        const float f1 = fbuf[1][t];
        const float4* c0 = reinterpret_cast<const float4*>(&cbuf[cur][0][cb][0]);
        const float4* c1 = reinterpret_cast<const float4*>(&cbuf[cur][1][cb][0]);

        v2f s0[4] = {{0.f, 0.f}, {0.f, 0.f}, {0.f, 0.f}, {0.f, 0.f}};
        v2f s1[4] = {{0.f, 0.f}, {0.f, 0.f}, {0.f, 0.f}, {0.f, 0.f}};
        #pragma unroll
        for (int q = 0; q < 16; ++q) {
            const float4 v0 = c0[q];
            const float4 v1 = c1[q];
            v2f v0lo = {v0.x, v0.y};
            v2f v0hi = {v0.z, v0.w};
            v2f v1lo = {v1.x, v1.y};
            v2f v1hi = {v1.z, v1.w};
            const int e = (q & 1) << 1;            // 0,2 alternating: 4 acc chains/seq
            s0[e]     += a2[2 * q]     * v0lo;     // v_pk_fma_f32
            s0[e + 1] += a2[2 * q + 1] * v0hi;
            s1[e]     += a2[2 * q]     * v1lo;
            s1[e + 1] += a2[2 * q + 1] * v1hi;
        }
        const v2f t0 = (s0[0] + s0[1]) + (s0[2] + s0[3]);
        const v2f t1 = (s1[0] + s1[1]) + (s1[2] + s1[3]);
        float p0 = t0.x + t0.y;
        float p1 = t1.x + t1.y;
        // reduce the 4 col-block partials (lanes 4r..4r+3) on the VALU pipe
        p0 = quad_reduce(p0);
        p1 = quad_reduce(p1);
        const float cn0 = fmaf(bd, f0, p0);
        const float cn1 = fmaf(bd, f1, p1);
        if (cb == 0) {
            cbuf[nxt][0][row >> 6][row & 63] = cn0;
            cbuf[nxt][1][row >> 6][row & 63] = cn1;
            float* o = outp + (size_t)t * (512 * 256);
            o[0]   = cn0;   // seq0,   state `row` at time t
            o[256] = cn1;   // seq0+1, state `row` at time t
        }
        __syncthreads();
    };

    for (int t = 0; t < LSTEPS; t += 2) {
        step(0, 1, t);       // read buf0 -> write buf1
        step(1, 0, t + 1);   // read buf1 -> write buf0
    }
}

extern "C" void kernel_launch(void* const* d_in, const int* in_sizes, int n_in,
                              void* d_out, int out_size, void* d_ws, size_t ws_size,
                              hipStream_t stream) {
    const float* inp = (const float*)d_in[0];   // (8,64,1024) fp32
    const float* A   = (const float*)d_in[1];   // (256,256)   fp32
    const float* B   = (const float*)d_in[2];   // (256,)      fp32
    float* out = (float*)d_out;                 // (1024,8,64,256) fp32
    hipLaunchKernelGGL(hippo_legt_kernel, dim3(256), dim3(1024), 0, stream,
                       inp, A, B, out);
}